// Round 1
// baseline (308.162 us; speedup 1.0000x reference)
//
#include <hip/hip_runtime.h>

// DEPTree: K=4, LEVELS=8, N=21845, D=128, NUM_POS=18, NUM_DEP=46
// Stage 1: x[n] = relu(emb[n] @ pos_W[pos_ids[n]] + pos_b[pos_ids[n]])
// Stage 2: bottom-up tree max-reduction with per-child GEMV vs dep_W[dep_ids].
// This round: fp32 wave-per-node GEMV baseline (L2-bound on W reads).

#define DD 128
#define NN 21845

// ---- Stage 1: one wave (64 lanes) per node; each lane computes 2 outputs ----
__global__ __launch_bounds__(256) void stage1_kernel(
        const float* __restrict__ emb,
        const int* __restrict__ pos_ids,
        const float* __restrict__ pos_W,
        const float* __restrict__ pos_b,
        float* __restrict__ x, int n) {
    int wid = (blockIdx.x * blockDim.x + threadIdx.x) >> 6;
    int lane = threadIdx.x & 63;
    int slot = threadIdx.x >> 6;
    if (wid >= n) return;
    __shared__ float sh[4][DD];
    // stage emb row into LDS for broadcast reads (intra-wave, no barrier needed)
    float2 e2 = *(const float2*)(emb + (size_t)wid * DD + lane * 2);
    sh[slot][lane * 2] = e2.x;
    sh[slot][lane * 2 + 1] = e2.y;
    int p = pos_ids[wid];
    const float* W = pos_W + (size_t)p * DD * DD;
    float2 b2 = *(const float2*)(pos_b + p * DD + lane * 2);
    float a0 = b2.x, a1 = b2.y;
#pragma unroll 8
    for (int d = 0; d < DD; ++d) {
        float zd = sh[slot][d];
        float2 w2 = *(const float2*)(W + d * DD + lane * 2);
        a0 = fmaf(zd, w2.x, a0);
        a1 = fmaf(zd, w2.y, a1);
    }
    float2 o;
    o.x = fmaxf(a0, 0.f);
    o.y = fmaxf(a1, 0.f);
    *(float2*)(x + (size_t)wid * DD + lane * 2) = o;
}

// ---- Stage 2 level kernel: one wave per PARENT; loops its 4 children ----
// m = max_j relu(child_j) computed as relu(max_j a_j) via m init 0 (all u>=0).
__global__ __launch_bounds__(256) void reduce_level_kernel(
        const float* __restrict__ z_in,     // [4^(l+1)][D]
        const float* __restrict__ x,        // full x buffer
        const int* __restrict__ dep_ids,
        const float* __restrict__ dep_W,
        const float* __restrict__ dep_b,
        float* __restrict__ z_out,          // [4^l][D]
        int n_parent, int s, int cs) {
    int wid = (blockIdx.x * blockDim.x + threadIdx.x) >> 6;
    int lane = threadIdx.x & 63;
    int slot = threadIdx.x >> 6;
    if (wid >= n_parent) return;
    __shared__ float sh[4][DD];
    float m0 = 0.f, m1 = 0.f;  // children are relu outputs (>=0): 0-init = fold relu
    for (int j = 0; j < 4; ++j) {
        int c = 4 * wid + j;
        float2 z2 = *(const float2*)(z_in + (size_t)c * DD + lane * 2);
        sh[slot][lane * 2] = z2.x;
        sh[slot][lane * 2 + 1] = z2.y;
        int did = dep_ids[cs + c];
        const float* W = dep_W + (size_t)did * DD * DD;
        float2 b2 = *(const float2*)(dep_b + did * DD + lane * 2);
        float a0 = b2.x, a1 = b2.y;
#pragma unroll 8
        for (int d = 0; d < DD; ++d) {
            float zd = sh[slot][d];
            float2 w2 = *(const float2*)(W + d * DD + lane * 2);
            a0 = fmaf(zd, w2.x, a0);
            a1 = fmaf(zd, w2.y, a1);
        }
        m0 = fmaxf(m0, a0);
        m1 = fmaxf(m1, a1);
    }
    float2 x2 = *(const float2*)(x + (size_t)(s + wid) * DD + lane * 2);
    float2 o;
    o.x = fmaxf(x2.x, m0);
    o.y = fmaxf(x2.y, m1);
    *(float2*)(z_out + (size_t)wid * DD + lane * 2) = o;
}

extern "C" void kernel_launch(void* const* d_in, const int* in_sizes, int n_in,
                              void* d_out, int out_size, void* d_ws, size_t ws_size,
                              hipStream_t stream) {
    const float* emb    = (const float*)d_in[0];
    const int*   pos_ids = (const int*)d_in[1];
    const int*   dep_ids = (const int*)d_in[2];
    const float* pos_W  = (const float*)d_in[3];
    const float* pos_b  = (const float*)d_in[4];
    const float* dep_W  = (const float*)d_in[5];
    const float* dep_b  = (const float*)d_in[6];
    float* out = (float*)d_out;

    float* x  = (float*)d_ws;                       // N*128 floats = 11.2 MB
    float* zA = x + (size_t)NN * DD;                // up to 4096*128 floats = 2 MB
    float* zB = zA + (size_t)4096 * DD;             // 2 MB

    // Stage 1: 21845 waves, 4 waves/block
    {
        int blocks = (NN + 3) / 4;
        stage1_kernel<<<blocks, 256, 0, stream>>>(emb, pos_ids, pos_W, pos_b, x, NN);
    }

    // level_start(l) = (4^l - 1)/3: 0,1,5,21,85,341,1365,5461
    // l=6: z_in = x slice at level 7 (no copy needed)
    const float* z_in = x + (size_t)5461 * DD;
    float* z_out = zA;
    // table of (n_parent, s, cs) for l=6..0
    const int np_tab[7] = {4096, 1024, 256, 64, 16, 4, 1};
    const int s_tab[7]  = {1365, 341, 85, 21, 5, 1, 0};
    const int cs_tab[7] = {5461, 1365, 341, 85, 21, 5, 1};
    for (int i = 0; i < 7; ++i) {
        float* dst = (i == 6) ? out : z_out;
        int blocks = (np_tab[i] + 3) / 4;
        reduce_level_kernel<<<blocks, 256, 0, stream>>>(
            z_in, x, dep_ids, dep_W, dep_b, dst, np_tab[i], s_tab[i], cs_tab[i]);
        z_in = z_out;
        z_out = (z_out == zA) ? zB : zA;
    }
}